// Round 1
// baseline (953.036 us; speedup 1.0000x reference)
//
#include <hip/hip_runtime.h>

#define BB 2048
#define TT 2048
typedef unsigned short u16;

// 16B POD for vectorized loads/stores with per-element access
struct F4 { float f[4]; };

// ---------------------------------------------------------------------------
// Phase 1: fully parallel elementwise pass.
//  - writes boundary_hit / boundary_decay (identical: active & bevent)
//  - prefills projected with anchor (scan overwrites active positions)
//  - emits compact scan inputs TRANSPOSED [T,B]: exT (f32), metaT (u16:
//    banchor int (bits 0..7) | active (bit 8) | bevent (bit 9))
//    banchor = max(round-valued budget,1) <= ~20 for this data, fits u8.
// Tile 64x64, 256 threads, LDS transpose (65-padded -> 2-way banks = free).
// ---------------------------------------------------------------------------
__global__ __launch_bounds__(256) void p1_tile(
    const float* __restrict__ ex_, const float* __restrict__ rnd_,
    const float* __restrict__ bud_, const float* __restrict__ sp_,
    const float* __restrict__ co_, const float* __restrict__ bd_,
    const float* __restrict__ pf_,
    float* __restrict__ proj, float* __restrict__ bhit, float* __restrict__ bdec,
    float* __restrict__ exT, u16* __restrict__ metaT)
{
    __shared__ float lex[64][65];
    __shared__ u16   lme[64][65];
    const int tid = threadIdx.x;
    const int tr = blockIdx.x & 31;   // row tile (b)
    const int tc = blockIdx.x >> 5;   // col tile (t)
    const int c4 = (tid & 15) << 2;   // 0..60
    const int r0 = tid >> 4;          // 0..15

#pragma unroll
    for (int rr = 0; rr < 4; ++rr) {
        const int rl = r0 + rr * 16;  // 0..63
        const size_t idx = (size_t)(tr * 64 + rl) * TT + (size_t)(tc * 64 + c4);
        F4 ex4 = *(const F4*)(ex_ + idx);
        F4 rn4 = *(const F4*)(rnd_ + idx);
        F4 bu4 = *(const F4*)(bud_ + idx);
        F4 sp4 = *(const F4*)(sp_ + idx);
        F4 co4 = *(const F4*)(co_ + idx);
        F4 bd4 = *(const F4*)(bd_ + idx);
        F4 pf4 = *(const F4*)(pf_ + idx);
        F4 pj, bh;
#pragma unroll
        for (int j = 0; j < 4; ++j) {
            const bool active = (sp4.f[j] > 0.5f) || (co4.f[j] > 0.5f);
            const bool bevent = (bd4.f[j] >= 0.5f) || (pf4.f[j] > 0.5f);
            const float anchor  = fmaxf(rn4.f[j], 1.0f);
            const float banchor = fmaxf(bu4.f[j], 1.0f);
            pj.f[j] = anchor;
            bh.f[j] = (active && bevent) ? 1.0f : 0.0f;
            lex[rl][c4 + j] = ex4.f[j];
            lme[rl][c4 + j] = (u16)((int)banchor | (active ? 0x100 : 0) | (bevent ? 0x200 : 0));
        }
        *(F4*)(proj + idx) = pj;
        *(F4*)(bhit + idx) = bh;
        *(F4*)(bdec + idx) = bh;
    }
    __syncthreads();
#pragma unroll
    for (int rr = 0; rr < 4; ++rr) {
        const int tl = r0 + rr * 16;  // t within tile
        F4 e;
        e.f[0] = lex[c4 + 0][tl]; e.f[1] = lex[c4 + 1][tl];
        e.f[2] = lex[c4 + 2][tl]; e.f[3] = lex[c4 + 3][tl];
        ushort4 mm;
        mm.x = lme[c4 + 0][tl]; mm.y = lme[c4 + 1][tl];
        mm.z = lme[c4 + 2][tl]; mm.w = lme[c4 + 3][tl];
        const size_t oidx = (size_t)(tc * 64 + tl) * BB + (size_t)(tr * 64 + c4);
        *(F4*)(exT + oidx) = e;
        *(ushort4*)(metaT + oidx) = mm;
    }
}

// ---------------------------------------------------------------------------
// Phase 2: serial scan, lane = row, 32 waves. Coalesced [T,B] loads with an
// 8-deep register prefetch pipeline. Exact reference arithmetic order.
// ---------------------------------------------------------------------------
#define PF 8
__global__ __launch_bounds__(64) void p2_scan(
    const float* __restrict__ exT, const u16* __restrict__ metaT,
    const float* __restrict__ ci, const float* __restrict__ oi,
    float* __restrict__ proj, float* __restrict__ cout, float* __restrict__ oout)
{
    const int lane = threadIdx.x;
    const int row = blockIdx.x * 64 + lane;
    float carry = ci[row];
    float off   = oi[row];
    float exq[PF]; int mq[PF];
#pragma unroll
    for (int i = 0; i < PF; ++i) {
        exq[i] = exT[(size_t)i * BB + row];
        mq[i]  = metaT[(size_t)i * BB + row];
    }
    float* projrow = proj + (size_t)row * TT;
    for (int t = 0; t < TT; t += PF) {
#pragma unroll
        for (int i = 0; i < PF; ++i) {
            const float ex = exq[i];
            const int   m  = mq[i];
            const int tn = t + PF + i;
            if (tn < TT) {
                exq[i] = exT[(size_t)tn * BB + row];
                mq[i]  = metaT[(size_t)tn * BB + row];
            }
            const float banchor = (float)(m & 255);
            const float scale = (m & 512) ? 0.5f : 1.0f;  // bevent ? 0.5 : 1
            // exact reference op order:
            const float lower = fmaxf(ceilf(banchor - (3.0f + off)), 1.0f);
            const float upper = fmaxf(floorf(banchor + (3.0f - off)), lower);
            const float total = fmaxf(ex + carry, 0.0f);
            // max(floor(total+0.5),1) folded: lower >= 1 always
            const float frames = fminf(fmaxf(floorf(total + 0.5f), lower), upper);
            const float nc = (total - frames) * scale;
            float no = (off + (frames - banchor)) * scale;
            no = fminf(fmaxf(no, -3.0f), 3.0f);  // clip; no-op when scale==1 (|no|<=3 invariant)
            if (m & 256) {               // active
                projrow[t + i] = frames;
                carry = nc;
                off = no;
            }
        }
    }
    cout[row] = carry;
    oout[row] = off;
}

// ---------------------------------------------------------------------------
// Fallback path (workspace too small): elementwise kernel + direct-read scan
// ---------------------------------------------------------------------------
__global__ __launch_bounds__(256) void p1_lite(
    const float* __restrict__ rnd_, const float* __restrict__ sp_,
    const float* __restrict__ co_, const float* __restrict__ bd_,
    const float* __restrict__ pf_,
    float* __restrict__ proj, float* __restrict__ bhit, float* __restrict__ bdec)
{
    const size_t n4 = (size_t)BB * TT / 4;
    for (size_t i = (size_t)blockIdx.x * blockDim.x + threadIdx.x; i < n4;
         i += (size_t)gridDim.x * blockDim.x) {
        F4 rn4 = ((const F4*)rnd_)[i];
        F4 sp4 = ((const F4*)sp_)[i];
        F4 co4 = ((const F4*)co_)[i];
        F4 bd4 = ((const F4*)bd_)[i];
        F4 pf4 = ((const F4*)pf_)[i];
        F4 pj, bh;
#pragma unroll
        for (int j = 0; j < 4; ++j) {
            const bool active = (sp4.f[j] > 0.5f) || (co4.f[j] > 0.5f);
            const bool bevent = (bd4.f[j] >= 0.5f) || (pf4.f[j] > 0.5f);
            pj.f[j] = fmaxf(rn4.f[j], 1.0f);
            bh.f[j] = (active && bevent) ? 1.0f : 0.0f;
        }
        ((F4*)proj)[i] = pj;
        ((F4*)bhit)[i] = bh;
        ((F4*)bdec)[i] = bh;
    }
}

__global__ __launch_bounds__(64) void p2_direct(
    const float* __restrict__ ex_, const float* __restrict__ bud_,
    const float* __restrict__ sp_, const float* __restrict__ co_,
    const float* __restrict__ bd_, const float* __restrict__ pf_,
    const float* __restrict__ ci, const float* __restrict__ oi,
    float* __restrict__ proj, float* __restrict__ cout, float* __restrict__ oout)
{
    const int row = blockIdx.x * 64 + threadIdx.x;
    float carry = ci[row];
    float off   = oi[row];
    const size_t base = (size_t)row * TT;
    for (int t = 0; t < TT; ++t) {
        const float ex = ex_[base + t];
        const float banchor = fmaxf(bud_[base + t], 1.0f);
        const bool active = (sp_[base + t] > 0.5f) || (co_[base + t] > 0.5f);
        const bool bevent = (bd_[base + t] >= 0.5f) || (pf_[base + t] > 0.5f);
        const float scale = bevent ? 0.5f : 1.0f;
        const float lower = fmaxf(ceilf(banchor - (3.0f + off)), 1.0f);
        const float upper = fmaxf(floorf(banchor + (3.0f - off)), lower);
        const float total = fmaxf(ex + carry, 0.0f);
        const float frames = fminf(fmaxf(floorf(total + 0.5f), lower), upper);
        const float nc = (total - frames) * scale;
        float no = (off + (frames - banchor)) * scale;
        no = fminf(fmaxf(no, -3.0f), 3.0f);
        if (active) {
            proj[base + t] = frames;
            carry = nc;
            off = no;
        }
    }
    cout[row] = carry;
    oout[row] = off;
}

// ---------------------------------------------------------------------------
extern "C" void kernel_launch(void* const* d_in, const int* in_sizes, int n_in,
                              void* d_out, int out_size, void* d_ws, size_t ws_size,
                              hipStream_t stream) {
    const float* ex  = (const float*)d_in[0];
    const float* rnd = (const float*)d_in[1];
    const float* bud = (const float*)d_in[2];
    const float* sp  = (const float*)d_in[3];
    const float* co  = (const float*)d_in[4];
    const float* bd  = (const float*)d_in[5];
    const float* pf  = (const float*)d_in[6];
    const float* ci  = (const float*)d_in[7];
    const float* oi  = (const float*)d_in[8];

    float* proj = (float*)d_out;
    float* bhit = proj + (size_t)BB * TT;
    float* bdec = bhit + (size_t)BB * TT;
    float* cout = bdec + (size_t)BB * TT;
    float* oout = cout + BB;

    const size_t need = (size_t)BB * TT * sizeof(float) + (size_t)BB * TT * sizeof(u16);
    if (ws_size >= need) {
        float* exT  = (float*)d_ws;
        u16* metaT  = (u16*)((char*)d_ws + (size_t)BB * TT * sizeof(float));
        p1_tile<<<1024, 256, 0, stream>>>(ex, rnd, bud, sp, co, bd, pf,
                                          proj, bhit, bdec, exT, metaT);
        p2_scan<<<32, 64, 0, stream>>>(exT, metaT, ci, oi, proj, cout, oout);
    } else {
        p1_lite<<<2048, 256, 0, stream>>>(rnd, sp, co, bd, pf, proj, bhit, bdec);
        p2_direct<<<32, 64, 0, stream>>>(ex, bud, sp, co, bd, pf, ci, oi,
                                         proj, cout, oout);
    }
}

// Round 2
// 331.491 us; speedup vs baseline: 2.8750x; 2.8750x over previous
//
#include <hip/hip_runtime.h>

#define BB 2048
#define TT 2048
#define NP (TT/2)   // t-pairs
typedef unsigned short u16;
typedef unsigned int u32;

struct F4 { float f[4]; };

// ---------------------------------------------------------------------------
// p1: parallel pass. Reads all 7 inputs tiled 64x64; writes bhit/bdec final
// values; emits packed scan inputs transposed pair-wise:
//   exP  [P][B] float2  (ex for t=2p, 2p+1)
//   metaP[P][B] u32     (two u16: banchor[0:6] | anchor[7:13] | active<<14 | bevent<<15)
// LDS transpose, f32 [64][65] layout -> 2-way banks (free).
// ---------------------------------------------------------------------------
__global__ __launch_bounds__(256) void p1_tile(
    const float* __restrict__ ex_, const float* __restrict__ rnd_,
    const float* __restrict__ bud_, const float* __restrict__ sp_,
    const float* __restrict__ co_, const float* __restrict__ bd_,
    const float* __restrict__ pf_,
    float* __restrict__ bhit, float* __restrict__ bdec,
    float2* __restrict__ exP, u32* __restrict__ metaP)
{
    __shared__ float lex[64][65];
    __shared__ u32   lme[64][65];
    const int tid = threadIdx.x;
    const int tr = blockIdx.x & 31;   // row tile
    const int tc = blockIdx.x >> 5;   // t tile
    const int c4 = (tid & 15) << 2;
    const int r0 = tid >> 4;

#pragma unroll
    for (int rr = 0; rr < 4; ++rr) {
        const int rl = r0 + rr * 16;
        const size_t idx = (size_t)(tr * 64 + rl) * TT + (size_t)(tc * 64 + c4);
        F4 ex4 = *(const F4*)(ex_ + idx);
        F4 rn4 = *(const F4*)(rnd_ + idx);
        F4 bu4 = *(const F4*)(bud_ + idx);
        F4 sp4 = *(const F4*)(sp_ + idx);
        F4 co4 = *(const F4*)(co_ + idx);
        F4 bd4 = *(const F4*)(bd_ + idx);
        F4 pf4 = *(const F4*)(pf_ + idx);
        F4 bh;
#pragma unroll
        for (int j = 0; j < 4; ++j) {
            const bool active = (sp4.f[j] > 0.5f) || (co4.f[j] > 0.5f);
            const bool bevent = (bd4.f[j] >= 0.5f) || (pf4.f[j] > 0.5f);
            int ban = (int)fmaxf(bu4.f[j], 1.0f); if (ban > 127) ban = 127;
            int anc = (int)fmaxf(rn4.f[j], 1.0f); if (anc > 127) anc = 127;
            bh.f[j] = (active && bevent) ? 1.0f : 0.0f;
            lex[rl][c4 + j] = ex4.f[j];
            lme[rl][c4 + j] = (u32)(ban | (anc << 7) | (active ? 1 << 14 : 0) |
                                    (bevent ? 1 << 15 : 0));
        }
        *(F4*)(bhit + idx) = bh;
        *(F4*)(bdec + idx) = bh;
    }
    __syncthreads();
#pragma unroll
    for (int it = 0; it < 8; ++it) {
        const int idx = it * 256 + tid;
        const int r = idx & 63;       // row within tile (= lane -> coalesced)
        const int p = idx >> 6;       // pair within tile, 0..31
        float2 e;
        e.x = lex[r][2 * p]; e.y = lex[r][2 * p + 1];
        const u32 m = lme[r][2 * p] | (lme[r][2 * p + 1] << 16);
        const size_t o = (size_t)(tc * 32 + p) * BB + (size_t)(tr * 64 + r);
        exP[o] = e;
        metaP[o] = m;
    }
}

// ---------------------------------------------------------------------------
// p2: serial scan. lane = row, 32 blocks x 64. 16-pair (32-step) register
// prefetch queue; 2 coalesced loads + 1 coalesced 8B store per pair.
// Result (active ? frames : anchor) written IN-PLACE over exP (same layout,
// write of pair p happens PF pairs after its last read; rows disjoint across
// waves -> race-free). restrict is legal: read-set and write-set are disjoint.
// ---------------------------------------------------------------------------
#define PF 16

__device__ __forceinline__ float step1(float ex, u32 m, float& carry, float& off) {
    const float banchor = (float)(m & 127);
    const float anchorf = (float)((m >> 7) & 127);
    const float scale   = (m & 0x8000u) ? 0.5f : 1.0f;   // bevent
    // exact reference op order:
    const float lower = fmaxf(ceilf(banchor - (3.0f + off)), 1.0f);
    const float upper = fmaxf(floorf(banchor + (3.0f - off)), lower);
    const float total = fmaxf(ex + carry, 0.0f);
    const float frames = fminf(fmaxf(floorf(total + 0.5f), lower), upper);
    const float nc = (total - frames) * scale;
    float no = (off + (frames - banchor)) * scale;
    no = fminf(fmaxf(no, -3.0f), 3.0f);   // no-op when scale==1 (|off|<=3 invariant)
    const bool act = (m & 0x4000u) != 0;
    carry = act ? nc : carry;
    off   = act ? no : off;
    return act ? frames : anchorf;
}

__global__ __launch_bounds__(64) void p2_scan(
    const float2* __restrict__ exPin, const u32* __restrict__ metaP,
    const float* __restrict__ ci, const float* __restrict__ oi,
    float2* __restrict__ projP,   // == exPin buffer, disjoint access sets
    float* __restrict__ cout, float* __restrict__ oout)
{
    const int row = blockIdx.x * 64 + threadIdx.x;
    float carry = ci[row];
    float off   = oi[row];
    const float2* pre = exPin + row;
    const u32*    prm = metaP + row;
    float2*       pw  = projP + row;

    float2 eq[PF]; u32 mq[PF];
#pragma unroll
    for (int i = 0; i < PF; ++i) {
        eq[i] = pre[(size_t)i * BB];
        mq[i] = prm[(size_t)i * BB];
    }
    int p = 0;
    for (; p < NP - PF; p += PF) {
#pragma unroll
        for (int i = 0; i < PF; ++i) {
            const float2 e = eq[i];
            const u32 m = mq[i];
            eq[i] = pre[(size_t)(p + PF + i) * BB];   // prefetch, unguarded
            mq[i] = prm[(size_t)(p + PF + i) * BB];
            float2 v;
            v.x = step1(e.x, m & 0xffffu, carry, off);
            v.y = step1(e.y, m >> 16, carry, off);
            pw[(size_t)(p + i) * BB] = v;
        }
    }
    // epilogue chunk: no prefetch
#pragma unroll
    for (int i = 0; i < PF; ++i) {
        const float2 e = eq[i];
        const u32 m = mq[i];
        float2 v;
        v.x = step1(e.x, m & 0xffffu, carry, off);
        v.y = step1(e.y, m >> 16, carry, off);
        pw[(size_t)(p + i) * BB] = v;
    }
    cout[row] = carry;
    oout[row] = off;
}

// ---------------------------------------------------------------------------
// p3: transpose projP [P][B] float2 -> proj [B][T] f32. Tiled 64x64 via LDS.
// ---------------------------------------------------------------------------
__global__ __launch_bounds__(256) void p3_transpose(
    const float2* __restrict__ projP, float* __restrict__ proj)
{
    __shared__ float l[64][65];
    const int tid = threadIdx.x;
    const int tr = blockIdx.x & 31;
    const int tc = blockIdx.x >> 5;
#pragma unroll
    for (int it = 0; it < 8; ++it) {
        const int idx = it * 256 + tid;
        const int r = idx & 63;
        const int p = idx >> 6;
        const float2 v = projP[(size_t)(tc * 32 + p) * BB + (size_t)(tr * 64 + r)];
        l[r][2 * p] = v.x;
        l[r][2 * p + 1] = v.y;
    }
    __syncthreads();
    const int c4 = (tid & 15) << 2;
    const int r0 = tid >> 4;
#pragma unroll
    for (int rr = 0; rr < 4; ++rr) {
        const int rl = r0 + rr * 16;
        F4 o;
        o.f[0] = l[rl][c4 + 0]; o.f[1] = l[rl][c4 + 1];
        o.f[2] = l[rl][c4 + 2]; o.f[3] = l[rl][c4 + 3];
        *(F4*)(proj + (size_t)(tr * 64 + rl) * TT + (size_t)(tc * 64 + c4)) = o;
    }
}

// ---------------------------------------------------------------------------
// Fallback (ws too small): elementwise + direct-read scan (known-correct).
// ---------------------------------------------------------------------------
__global__ __launch_bounds__(256) void p1_lite(
    const float* __restrict__ rnd_, const float* __restrict__ sp_,
    const float* __restrict__ co_, const float* __restrict__ bd_,
    const float* __restrict__ pf_,
    float* __restrict__ proj, float* __restrict__ bhit, float* __restrict__ bdec)
{
    const size_t n4 = (size_t)BB * TT / 4;
    for (size_t i = (size_t)blockIdx.x * blockDim.x + threadIdx.x; i < n4;
         i += (size_t)gridDim.x * blockDim.x) {
        F4 rn4 = ((const F4*)rnd_)[i];
        F4 sp4 = ((const F4*)sp_)[i];
        F4 co4 = ((const F4*)co_)[i];
        F4 bd4 = ((const F4*)bd_)[i];
        F4 pf4 = ((const F4*)pf_)[i];
        F4 pj, bh;
#pragma unroll
        for (int j = 0; j < 4; ++j) {
            const bool active = (sp4.f[j] > 0.5f) || (co4.f[j] > 0.5f);
            const bool bevent = (bd4.f[j] >= 0.5f) || (pf4.f[j] > 0.5f);
            pj.f[j] = fmaxf(rn4.f[j], 1.0f);
            bh.f[j] = (active && bevent) ? 1.0f : 0.0f;
        }
        ((F4*)proj)[i] = pj;
        ((F4*)bhit)[i] = bh;
        ((F4*)bdec)[i] = bh;
    }
}

__global__ __launch_bounds__(64) void p2_direct(
    const float* __restrict__ ex_, const float* __restrict__ bud_,
    const float* __restrict__ sp_, const float* __restrict__ co_,
    const float* __restrict__ bd_, const float* __restrict__ pf_,
    const float* __restrict__ ci, const float* __restrict__ oi,
    float* __restrict__ proj, float* __restrict__ cout, float* __restrict__ oout)
{
    const int row = blockIdx.x * 64 + threadIdx.x;
    float carry = ci[row];
    float off   = oi[row];
    const size_t base = (size_t)row * TT;
    for (int t = 0; t < TT; ++t) {
        const float ex = ex_[base + t];
        const float banchor = fmaxf(bud_[base + t], 1.0f);
        const bool active = (sp_[base + t] > 0.5f) || (co_[base + t] > 0.5f);
        const bool bevent = (bd_[base + t] >= 0.5f) || (pf_[base + t] > 0.5f);
        const float scale = bevent ? 0.5f : 1.0f;
        const float lower = fmaxf(ceilf(banchor - (3.0f + off)), 1.0f);
        const float upper = fmaxf(floorf(banchor + (3.0f - off)), lower);
        const float total = fmaxf(ex + carry, 0.0f);
        const float frames = fminf(fmaxf(floorf(total + 0.5f), lower), upper);
        const float nc = (total - frames) * scale;
        float no = (off + (frames - banchor)) * scale;
        no = fminf(fmaxf(no, -3.0f), 3.0f);
        if (active) {
            proj[base + t] = frames;
            carry = nc;
            off = no;
        }
    }
    cout[row] = carry;
    oout[row] = off;
}

// ---------------------------------------------------------------------------
extern "C" void kernel_launch(void* const* d_in, const int* in_sizes, int n_in,
                              void* d_out, int out_size, void* d_ws, size_t ws_size,
                              hipStream_t stream) {
    const float* ex  = (const float*)d_in[0];
    const float* rnd = (const float*)d_in[1];
    const float* bud = (const float*)d_in[2];
    const float* sp  = (const float*)d_in[3];
    const float* co  = (const float*)d_in[4];
    const float* bd  = (const float*)d_in[5];
    const float* pf  = (const float*)d_in[6];
    const float* ci  = (const float*)d_in[7];
    const float* oi  = (const float*)d_in[8];

    float* proj = (float*)d_out;
    float* bhit = proj + (size_t)BB * TT;
    float* bdec = bhit + (size_t)BB * TT;
    float* cout = bdec + (size_t)BB * TT;
    float* oout = cout + BB;

    const size_t exP_bytes = (size_t)NP * BB * sizeof(float2);   // 16 MB
    const size_t meta_bytes = (size_t)NP * BB * sizeof(u32);     //  8 MB
    if (ws_size >= exP_bytes + meta_bytes) {
        float2* exP = (float2*)d_ws;
        u32* metaP  = (u32*)((char*)d_ws + exP_bytes);
        p1_tile<<<1024, 256, 0, stream>>>(ex, rnd, bud, sp, co, bd, pf,
                                          bhit, bdec, exP, metaP);
        p2_scan<<<32, 64, 0, stream>>>(exP, metaP, ci, oi, exP /*in-place*/,
                                       cout, oout);
        p3_transpose<<<1024, 256, 0, stream>>>(exP, proj);
    } else {
        p1_lite<<<2048, 256, 0, stream>>>(rnd, sp, co, bd, pf, proj, bhit, bdec);
        p2_direct<<<32, 64, 0, stream>>>(ex, bud, sp, co, bd, pf, ci, oi,
                                         proj, cout, oout);
    }
}